// Round 4
// baseline (451.975 us; speedup 1.0000x reference)
//
#include <hip/hip_runtime.h>
#include <hip/hip_bf16.h>
#include <cstdint>
#include <cstddef>

// TripletLoss: inputs (8192,128) fp32, targets (8192,) int32, 64 classes.
// out[0] = loss, out[1..] = dist (8192x8192) row-major fp32.
// v5: concurrency fix. v1-v4 all ran 2 blocks/CU (64KB LDS) with serialized
// barrier phases -> per-block latency ~43K cycles for ~7K cycles of work
// (Little's law at 150us/4096 blocks); store-path changes only moved +-15%.
// Changes:
//  (1) no A/B LDS staging: MFMA fragments load straight from global (Xb is
//      2MB, L2/L3-resident; v3 proved this costs nothing) -> one less barrier.
//  (2) C staged through 32KB LDS in two 64-row halves -> LDS 33KB ->
//      4 blocks/CU (16 waves/CU), 2x latency hiding. launch_bounds(256,4).
//  (3) grid bn-fast: co-resident blocks span all 64 column positions ->
//      write stream covers all HBM channels + dense contiguous write front.
//  (4) keep v4: regular (L2-allocating) stores, aligned shifted row stores,
//      zero-shuffle column-register reduce.

#define NROWS 8192
#define DIMK  128
#define MARGIN 0.3f

typedef __bf16 bf16x8 __attribute__((ext_vector_type(8)));
typedef float  f32x4  __attribute__((ext_vector_type(4)));
typedef float  f32x2  __attribute__((ext_vector_type(2)));
typedef int    i32x4  __attribute__((ext_vector_type(4)));

__device__ __forceinline__ unsigned short f2bf(float f) {
    // round-to-nearest-even fp32 -> bf16
    unsigned u = __float_as_uint(f);
    u += 0x7fffu + ((u >> 16) & 1u);
    return (unsigned short)(u >> 16);
}

// prep: bf16-convert X into LINEAR Xb (no swizzle needed; no LDS staging in
// dist anymore), row sq-norms from the ROUNDED values, init ap/an.
__global__ __launch_bounds__(256) void prep_kernel(
    const float* __restrict__ X, unsigned short* __restrict__ Xb,
    float* __restrict__ sq, int* __restrict__ ap, int* __restrict__ an)
{
    const int t = blockIdx.x * 256 + threadIdx.x;
    if (t < NROWS) { ap[t] = 0; an[t] = 0x7f800000; }  // 0.0f / +inf
    const int row  = t >> 6;
    const int lane = t & 63;
    const f32x2 v = *(const f32x2*)(X + (size_t)row * DIMK + lane * 2);
    const unsigned short b0 = f2bf(v[0]);
    const unsigned short b1 = f2bf(v[1]);
    *(unsigned*)(Xb + (size_t)row * DIMK + lane * 2) =
        (unsigned)b0 | ((unsigned)b1 << 16);
    const float f0 = __uint_as_float((unsigned)b0 << 16);
    const float f1 = __uint_as_float((unsigned)b1 << 16);
    float s = f0 * f0 + f1 * f1;
    #pragma unroll
    for (int off = 32; off; off >>= 1) s += __shfl_xor(s, off);
    if (lane == 0) sq[row] = s;
}

// shifted row store: dist base is out+1, so per lane write [4rc-1, 4rc+3)
// (16B aligned) with the missing element pulled from the left neighbor.
__device__ __forceinline__ void store_row_shifted(float* drow, f32x4 d4, int rc) {
    const float prev = __shfl_up(d4[3], 1);
    if (rc == 0) {
        drow[0] = d4[0];
        *(f32x2*)(drow + 1) = (f32x2){d4[1], d4[2]};
    } else {
        *(f32x4*)(drow + (rc << 2) - 1) = (f32x4){prev, d4[0], d4[1], d4[2]};
    }
    if (rc == 31)
        drow[127] = d4[3];
}

__global__ __launch_bounds__(256, 4) void dist_kernel(
    const unsigned short* __restrict__ Xb, const float* __restrict__ sq,
    const int* __restrict__ tgt, float* __restrict__ dist,
    int* __restrict__ ap, int* __restrict__ an)
{
    __shared__ __align__(16) char lds[32 * 1024];  // C half-tile f32 64x128
    __shared__ int apL[128], anL[128];

    const int t  = threadIdx.x;
    const int bn = blockIdx.x, bm = blockIdx.y;    // bn FAST (channel spread)

    if (t < 128) { apL[t] = 0; anL[t] = 0x7f800000; }

    const int lane = t & 63, wave = t >> 6;
    const int wm = (wave >> 1) << 6;   // 0 or 64
    const int wn = (wave & 1) << 6;
    const int l15 = lane & 15, quad = lane >> 4;
    const int rbase = bm << 7, cbase = bn << 7;
    const float INF = __int_as_float(0x7f800000);

    // ---- MFMA: fragments direct from global (L2-resident, no staging) ----
    f32x4 acc[4][4];
    #pragma unroll
    for (int mi = 0; mi < 4; mi++)
        #pragma unroll
        for (int ni = 0; ni < 4; ni++)
            acc[mi][ni] = (f32x4){0.f, 0.f, 0.f, 0.f};

    const unsigned short* Arow = Xb + (size_t)(rbase + wm + l15) * DIMK;
    const unsigned short* Brow = Xb + (size_t)(cbase + wn + l15) * DIMK;
    #pragma unroll
    for (int ks = 0; ks < 4; ks++) {
        const int kb = ks * 32 + quad * 8;
        bf16x8 af[4], bfr[4];
        #pragma unroll
        for (int mi = 0; mi < 4; mi++)
            af[mi] = *(const bf16x8*)(Arow + mi * 16 * DIMK + kb);
        #pragma unroll
        for (int ni = 0; ni < 4; ni++)
            bfr[ni] = *(const bf16x8*)(Brow + ni * 16 * DIMK + kb);
        #pragma unroll
        for (int mi = 0; mi < 4; mi++)
            #pragma unroll
            for (int ni = 0; ni < 4; ni++)
                acc[mi][ni] = __builtin_amdgcn_mfma_f32_16x16x32_bf16(
                    af[mi], bfr[ni], acc[mi][ni], 0, 0, 0);
    }

    // ---- convert sqd -> d in place ----
    // C/D layout: col = lane&15, row = quad*4 + reg (per frag).
    int lcv[4]; float sqc[4];
    #pragma unroll
    for (int ni = 0; ni < 4; ni++) {
        lcv[ni] = wn + ni * 16 + l15;          // local col 0..127
        sqc[ni] = sq[cbase + lcv[ni]];
    }
    #pragma unroll
    for (int mi = 0; mi < 4; mi++) {
        const int rl0 = wm + mi * 16 + quad * 4;
        const f32x4 sqr = *(const f32x4*)(sq + rbase + rl0);
        #pragma unroll
        for (int reg = 0; reg < 4; reg++) {
            const int rl = rl0 + reg;          // local row 0..127
            const int rg = rbase + rl;
            #pragma unroll
            for (int ni = 0; ni < 4; ni++) {
                const float sqd = sqr[reg] + sqc[ni] - 2.0f * acc[mi][ni][reg];
                float d = sqd > 0.0f ? sqrtf(sqd) : 0.0f;
                if (rg == cbase + lcv[ni]) d = 0.0f;   // exact diagonal
                acc[mi][ni][reg] = d;
            }
        }
    }

    // ---- two 64-row halves through 32KB LDS: stage, readback, reduce ----
    const int rc = t & 31;                 // fixed 16B col-chunk (cols 4rc..)
    const int w  = t >> 5;                 // row subset selector 0..7
    float apv[4] = {-1.f, -1.f, -1.f, -1.f};
    float anv[4] = {INF, INF, INF, INF};
    const i32x4 tc = *(const i32x4*)(tgt + cbase + rc * 4);

    #pragma unroll
    for (int h = 0; h < 2; h++) {
        if (wm == h * 64) {                // the 2 waves owning rows of half h
            #pragma unroll
            for (int mi = 0; mi < 4; mi++) {
                #pragma unroll
                for (int reg = 0; reg < 4; reg++) {
                    const int rl = mi * 16 + quad * 4 + reg;   // local 0..63
                    const int sw = (rl & 7) << 4;
                    #pragma unroll
                    for (int ni = 0; ni < 4; ni++)
                        *(float*)(lds + rl * 512 + ((lcv[ni] << 2) ^ sw)) =
                            acc[mi][ni][reg];
                }
            }
        }
        __syncthreads();
        #pragma unroll
        for (int it = 0; it < 8; it++) {
            const int r = it * 8 + w;      // local row 0..63
            const f32x4 d4 = *(const f32x4*)(
                lds + r * 512 + (((rc) << 4) ^ ((r & 7) << 4)));
            const int rowg = rbase + h * 64 + r;
            store_row_shifted(dist + (size_t)rowg * NROWS + cbase, d4, rc);
            const int trg = tgt[rowg];
            #pragma unroll
            for (int j = 0; j < 4; j++) {
                const bool same = (trg == tc[j]);
                apv[j] = fmaxf(apv[j], same ? d4[j] : -1.f);
                anv[j] = fminf(anv[j], same ? INF : d4[j]);
            }
        }
        __syncthreads();
    }

    // combine half-wave partials, cross-wave via LDS atomics, 1 global/thread
    #pragma unroll
    for (int j = 0; j < 4; j++) {
        apv[j] = fmaxf(apv[j], __shfl_xor(apv[j], 32));
        anv[j] = fminf(anv[j], __shfl_xor(anv[j], 32));
    }
    if (lane < 32) {
        #pragma unroll
        for (int j = 0; j < 4; j++) {
            atomicMax(apL + rc * 4 + j, __float_as_int(apv[j]));
            atomicMin(anL + rc * 4 + j, __float_as_int(anv[j]));
        }
    }
    __syncthreads();
    if (t < 128) {
        atomicMax(ap + cbase + t, apL[t]);
        atomicMin(an + cbase + t, anL[t]);
    }
}

__global__ __launch_bounds__(256) void loss_kernel(
    const int* __restrict__ ap, const int* __restrict__ an,
    float* __restrict__ out)
{
    __shared__ float red[4];
    float s = 0.0f;
    for (int i = threadIdx.x; i < NROWS; i += 256) {
        const float v = __int_as_float(ap[i]) - __int_as_float(an[i]) + MARGIN;
        s += v > 0.0f ? v : 0.0f;
    }
    #pragma unroll
    for (int off = 32; off; off >>= 1) s += __shfl_xor(s, off);
    if ((threadIdx.x & 63) == 0) red[threadIdx.x >> 6] = s;
    __syncthreads();
    if (threadIdx.x == 0)
        out[0] = (red[0] + red[1] + red[2] + red[3]) * (1.0f / NROWS);
}

extern "C" void kernel_launch(void* const* d_in, const int* in_sizes, int n_in,
                              void* d_out, int out_size, void* d_ws, size_t ws_size,
                              hipStream_t stream)
{
    const float* X   = (const float*)d_in[0];
    const int*   tgt = (const int*)d_in[1];
    float*       out = (float*)d_out;

    // ws layout: Xb bf16 8192x128 linear (2 MB) | sq (32 KB) | ap | an
    unsigned short* Xb = (unsigned short*)d_ws;
    float* sq = (float*)((char*)d_ws + (size_t)NROWS * DIMK * 2);
    int*   ap = (int*)(sq + NROWS);
    int*   an = ap + NROWS;

    prep_kernel<<<(NROWS * 64) / 256, 256, 0, stream>>>(X, Xb, sq, ap, an);

    dim3 grid(64, 64);   // x = bn (fast), y = bm
    dist_kernel<<<grid, 256, 0, stream>>>(Xb, sq, tgt, out + 1, ap, an);

    loss_kernel<<<1, 256, 0, stream>>>(ap, an, out);
}